// Round 1
// baseline (832.169 us; speedup 1.0000x reference)
//
#include <hip/hip_runtime.h>

// Problem constants
constexpr int NB  = 4;
constexpr int NH  = 12;
constexpr int SEQ = 1024;   // LQ == LK
constexpr int DKd = 64;
constexpr int DVd = 768;
constexpr int Ed  = 768;    // E == H*DK
constexpr int HVd = 9216;   // H*DV

typedef float f32x4 __attribute__((ext_vector_type(4)));
typedef short s16x8 __attribute__((ext_vector_type(8)));

__device__ __forceinline__ unsigned short f2bf(float f) {
  unsigned int u = __builtin_bit_cast(unsigned int, f);
  u += 0x7fffu + ((u >> 16) & 1u);          // RNE
  return (unsigned short)(u >> 16);
}

__device__ __forceinline__ f32x4 mfma_bf16_16x16x32(s16x8 a, s16x8 b, f32x4 c) {
  asm("v_mfma_f32_16x16x32_bf16 %0, %1, %2, %0" : "+v"(c) : "v"(a), "v"(b));
  return c;
}

// ---------------------------------------------------------------------------
// fp32 GEMM: C[M,N] = A[M,K] @ B[K,N]  (used for qh = q@w_qs, kh = k@w_ks)
// 128x128 tile, BK=8, 256 threads, 8x8 micro-tile.
// ---------------------------------------------------------------------------
__global__ __launch_bounds__(256)
void gemm_f32_kernel(const float* __restrict__ A, const float* __restrict__ Bw,
                     float* __restrict__ C, int M, int K, int N) {
  __shared__ float As[8][128];   // [k][m]
  __shared__ float Bs[8][128];   // [k][n]
  const int tid = threadIdx.x;
  const int m0 = blockIdx.x * 128, n0 = blockIdx.y * 128;
  const int ty = tid >> 4, tx = tid & 15;
  const int arow = tid >> 1, akc = (tid & 1) * 4;
  const int brow = tid >> 5, bnc = (tid & 31) * 4;

  float acc[8][8];
#pragma unroll
  for (int i = 0; i < 8; i++)
#pragma unroll
    for (int j = 0; j < 8; j++) acc[i][j] = 0.f;

  for (int k0 = 0; k0 < K; k0 += 8) {
    const f32x4 av = *(const f32x4*)&A[(size_t)(m0 + arow) * K + k0 + akc];
    const f32x4 bv = *(const f32x4*)&Bw[(size_t)(k0 + brow) * N + n0 + bnc];
    __syncthreads();
    As[akc + 0][arow] = av[0];
    As[akc + 1][arow] = av[1];
    As[akc + 2][arow] = av[2];
    As[akc + 3][arow] = av[3];
    *(f32x4*)&Bs[brow][bnc] = bv;
    __syncthreads();
#pragma unroll
    for (int kk = 0; kk < 8; kk++) {
      const f32x4 a0 = *(const f32x4*)&As[kk][ty * 8];
      const f32x4 a1 = *(const f32x4*)&As[kk][ty * 8 + 4];
      const f32x4 b0 = *(const f32x4*)&Bs[kk][tx * 8];
      const f32x4 b1 = *(const f32x4*)&Bs[kk][tx * 8 + 4];
#pragma unroll
      for (int i = 0; i < 4; i++)
#pragma unroll
        for (int j = 0; j < 4; j++) {
          acc[i][j]         += a0[i] * b0[j];
          acc[i][j + 4]     += a0[i] * b1[j];
          acc[i + 4][j]     += a1[i] * b0[j];
          acc[i + 4][j + 4] += a1[i] * b1[j];
        }
    }
  }
#pragma unroll
  for (int i = 0; i < 8; i++) {
    f32x4 o0, o1;
#pragma unroll
    for (int c = 0; c < 4; c++) { o0[c] = acc[i][c]; o1[c] = acc[i][4 + c]; }
    const size_t rb = (size_t)(m0 + ty * 8 + i) * N + n0 + tx * 8;
    *(f32x4*)&C[rb] = o0;
    *(f32x4*)&C[rb + 4] = o1;
  }
}

// ---------------------------------------------------------------------------
// Scores + per-128-k-block argmax (masked):
// S[q,k] = dot(qh[b,q,h,:], kh[b,k,h,:]) / 8 + qk_mask[b,q,k] + k_mask[b,k]
// candidates only where post_softmax_mask > 0.  Writes (val,idx) partials.
// One block = 128 q x 128 k of one (b,h).  K-dim = 64, single pass.
// ---------------------------------------------------------------------------
__global__ __launch_bounds__(256)
void score_argmax_kernel(const float* __restrict__ qh, const float* __restrict__ kh,
                         const float* __restrict__ qk_mask, const float* __restrict__ k_mask,
                         const float* __restrict__ pmask, float2* __restrict__ partials) {
  __shared__ float QsT[64][128];   // [d][q]
  __shared__ float KsT[64][128];   // [d][k]
  const int bh = blockIdx.z;                 // b*NH + h
  const int b = bh / NH, h = bh % NH;
  const int q0 = blockIdx.y * 128;
  const int k0 = blockIdx.x * 128;
  const int tid = threadIdx.x;
  const int ty = tid >> 4, tx = tid & 15;

  // stage qh / kh tiles transposed
  const int row = tid >> 1;
  const int cb = (tid & 1) * 32;
  const float* qsrc = qh + (size_t)(b * SEQ + q0 + row) * Ed + h * DKd + cb;
  const float* ksrc = kh + (size_t)(b * SEQ + k0 + row) * Ed + h * DKd + cb;
#pragma unroll
  for (int i = 0; i < 8; i++) {
    const f32x4 qv = *(const f32x4*)&qsrc[4 * i];
    const f32x4 kv = *(const f32x4*)&ksrc[4 * i];
#pragma unroll
    for (int c = 0; c < 4; c++) {
      QsT[cb + 4 * i + c][row] = qv[c];
      KsT[cb + 4 * i + c][row] = kv[c];
    }
  }
  __syncthreads();

  float acc[8][8];
#pragma unroll
  for (int i = 0; i < 8; i++)
#pragma unroll
    for (int j = 0; j < 8; j++) acc[i][j] = 0.f;

#pragma unroll 8
  for (int kk = 0; kk < 64; kk++) {
    const f32x4 a0 = *(const f32x4*)&QsT[kk][ty * 8];
    const f32x4 a1 = *(const f32x4*)&QsT[kk][ty * 8 + 4];
    const f32x4 b0 = *(const f32x4*)&KsT[kk][tx * 8];
    const f32x4 b1 = *(const f32x4*)&KsT[kk][tx * 8 + 4];
#pragma unroll
    for (int i = 0; i < 4; i++)
#pragma unroll
      for (int j = 0; j < 4; j++) {
        acc[i][j]         += a0[i] * b0[j];
        acc[i][j + 4]     += a0[i] * b1[j];
        acc[i + 4][j]     += a1[i] * b0[j];
        acc[i + 4][j + 4] += a1[i] * b1[j];
      }
  }

  const int kg0 = k0 + tx * 8;
  const f32x4 km0 = *(const f32x4*)&k_mask[b * SEQ + kg0];
  const f32x4 km1 = *(const f32x4*)&k_mask[b * SEQ + kg0 + 4];
#pragma unroll
  for (int i = 0; i < 8; i++) {
    const int qg = q0 + ty * 8 + i;
    const size_t base = (size_t)(b * SEQ + qg) * SEQ + kg0;
    const f32x4 qm0 = *(const f32x4*)&qk_mask[base];
    const f32x4 qm1 = *(const f32x4*)&qk_mask[base + 4];
    const f32x4 pm0 = *(const f32x4*)&pmask[base];
    const f32x4 pm1 = *(const f32x4*)&pmask[base + 4];
    float bv = -3.0e38f;
    int bi = 0;
#pragma unroll
    for (int j = 0; j < 4; j++) {
      const float s = acc[i][j] * 0.125f + qm0[j] + km0[j];
      if (pm0[j] > 0.f && s > bv) { bv = s; bi = kg0 + j; }
    }
#pragma unroll
    for (int j = 0; j < 4; j++) {
      const float s = acc[i][4 + j] * 0.125f + qm1[j] + km1[j];
      if (pm1[j] > 0.f && s > bv) { bv = s; bi = kg0 + 4 + j; }
    }
    // reduce across the 16 threads (tx) sharing this q row
#pragma unroll
    for (int off = 1; off < 16; off <<= 1) {
      const float ov = __shfl_xor(bv, off);
      const int   oi = __shfl_xor(bi, off);
      if (ov > bv || (ov == bv && oi < bi)) { bv = ov; bi = oi; }
    }
    if (tx == 0)
      partials[(size_t)(bh * SEQ + qg) * 8 + blockIdx.x] =
          make_float2(bv, __int_as_float(bi));
  }
}

__global__ __launch_bounds__(256)
void argmax_reduce_kernel(const float2* __restrict__ partials, int* __restrict__ kmaxp) {
  const int t = blockIdx.x * 256 + threadIdx.x;
  if (t >= NB * NH * SEQ) return;
  const float2* p = partials + (size_t)t * 8;
  float bv = -3.0e38f;
  int bi = 0;
#pragma unroll
  for (int i = 0; i < 8; i++) {
    const float vv = p[i].x;
    const int ii = __float_as_int(p[i].y);
    if (vv > bv) { bv = vv; bi = ii; }   // strict >: keeps lowest index (idx ascends with i)
  }
  kmaxp[t] = bi;
}

// ---------------------------------------------------------------------------
// M_h = w_vs[:, h*768:+768] @ fc[h*768:+768, :]  -> Mstb (bf16), per-head.
// bf16 MFMA 16x16x32, 128x128 tile, BK=64, 4 waves (2x2), 4x4 frags/wave.
// ---------------------------------------------------------------------------
__global__ __launch_bounds__(256)
void wvfc_gemm_kernel(const float* __restrict__ wvs, const float* __restrict__ fcw,
                      unsigned short* __restrict__ Mstb) {
  __shared__ unsigned short As[128][72];   // [m][k]  (+8 pad)
  __shared__ unsigned short Bs[128][72];   // [n][k]  (transposed B)
  const int tid = threadIdx.x;
  const int h = blockIdx.z;
  const int m0 = blockIdx.x * 128, n0 = blockIdx.y * 128;
  const int wid = tid >> 6, lane = tid & 63;
  const int wr = (wid >> 1) * 64, wc = (wid & 1) * 64;
  const int lm = lane & 15, lq = lane >> 4;
  const int ar = tid >> 1, acb = (tid & 1) * 32;
  const int br = tid >> 2, bnb = (tid & 3) * 32;

  f32x4 acc[4][4];
#pragma unroll
  for (int m = 0; m < 4; m++)
#pragma unroll
    for (int n = 0; n < 4; n++)
#pragma unroll
      for (int r = 0; r < 4; r++) acc[m][n][r] = 0.f;

  for (int k0 = 0; k0 < 768; k0 += 64) {
    const float* asrc = wvs + (size_t)(m0 + ar) * HVd + h * 768 + k0 + acb;
    const float* bsrc = fcw + (size_t)(h * 768 + k0 + br) * 768 + n0 + bnb;
    f32x4 a4[8], b4[8];
#pragma unroll
    for (int i = 0; i < 8; i++) a4[i] = *(const f32x4*)&asrc[4 * i];
#pragma unroll
    for (int i = 0; i < 8; i++) b4[i] = *(const f32x4*)&bsrc[4 * i];
    __syncthreads();
#pragma unroll
    for (int i = 0; i < 4; i++) {
      s16x8 pk;
#pragma unroll
      for (int j = 0; j < 8; j++) pk[j] = (short)f2bf(a4[2 * i + (j >> 2)][j & 3]);
      *(s16x8*)&As[ar][acb + 8 * i] = pk;
    }
#pragma unroll
    for (int i = 0; i < 8; i++)
#pragma unroll
      for (int c = 0; c < 4; c++) Bs[bnb + 4 * i + c][br] = f2bf(b4[i][c]);
    __syncthreads();
#pragma unroll
    for (int ks = 0; ks < 2; ks++) {
      s16x8 af[4], bf[4];
#pragma unroll
      for (int m = 0; m < 4; m++)
        af[m] = *(const s16x8*)&As[wr + m * 16 + lm][ks * 32 + lq * 8];
#pragma unroll
      for (int n = 0; n < 4; n++)
        bf[n] = *(const s16x8*)&Bs[wc + n * 16 + lm][ks * 32 + lq * 8];
#pragma unroll
      for (int m = 0; m < 4; m++)
#pragma unroll
        for (int n = 0; n < 4; n++)
          acc[m][n] = mfma_bf16_16x16x32(af[m], bf[n], acc[m][n]);
    }
  }
  asm volatile("s_nop 7\n\ts_nop 7");
#pragma unroll
  for (int m = 0; m < 4; m++)
#pragma unroll
    for (int n = 0; n < 4; n++)
#pragma unroll
      for (int r = 0; r < 4; r++) {
        const int grow = m0 + wr + m * 16 + lq * 4 + r;   // d index
        const int gcol = n0 + wc + n * 16 + lm;           // output index
        Mstb[(size_t)(h * 768 + grow) * 768 + gcol] = f2bf(acc[m][n][r]);
      }
}

// ---------------------------------------------------------------------------
// out0[bq, :] = sum_h v[b, kmax[b,h,q], :] @ M_h + v[bq, :]
// = GatheredV[4096, 9216] @ Mstb[9216, 768] + v.   A is gathered on the fly.
// ---------------------------------------------------------------------------
__global__ __launch_bounds__(256)
void gather_gemm_kernel(const float* __restrict__ v, const unsigned short* __restrict__ Mstb,
                        const int* __restrict__ kmaxp, float* __restrict__ out0) {
  __shared__ unsigned short As[128][72];
  __shared__ unsigned short Bs[128][72];
  const int tid = threadIdx.x;
  const int m0 = blockIdx.x * 128, n0 = blockIdx.y * 128;
  const int wid = tid >> 6, lane = tid & 63;
  const int wr = (wid >> 1) * 64, wc = (wid & 1) * 64;
  const int lm = lane & 15, lq = lane >> 4;
  const int ar = tid >> 1, acb = (tid & 1) * 32;
  const int br = tid >> 2, bnb = (tid & 3) * 32;
  const int mrow = m0 + ar;
  const int bb = mrow >> 10, qq = mrow & 1023;
  const int kb0 = (bb * NH) << 10;

  f32x4 acc[4][4];
#pragma unroll
  for (int m = 0; m < 4; m++)
#pragma unroll
    for (int n = 0; n < 4; n++)
#pragma unroll
      for (int r = 0; r < 4; r++) acc[m][n][r] = 0.f;

  int h = 0, kloc = 0;
  for (int k0 = 0; k0 < HVd; k0 += 64) {
    const int kidx = kmaxp[kb0 + (h << 10) + qq];
    const float* asrc = v + (size_t)((bb << 10) + kidx) * 768 + kloc + acb;
    const unsigned short* bsrc = Mstb + (size_t)(k0 + br) * 768 + n0 + bnb;
    f32x4 a4[8];
    s16x8 b4[4];
#pragma unroll
    for (int i = 0; i < 8; i++) a4[i] = *(const f32x4*)&asrc[4 * i];
#pragma unroll
    for (int i = 0; i < 4; i++) b4[i] = *(const s16x8*)&bsrc[8 * i];
    __syncthreads();
#pragma unroll
    for (int i = 0; i < 4; i++) {
      s16x8 pk;
#pragma unroll
      for (int j = 0; j < 8; j++) pk[j] = (short)f2bf(a4[2 * i + (j >> 2)][j & 3]);
      *(s16x8*)&As[ar][acb + 8 * i] = pk;
    }
#pragma unroll
    for (int i = 0; i < 4; i++)
#pragma unroll
      for (int c = 0; c < 8; c++) Bs[bnb + 8 * i + c][br] = (unsigned short)b4[i][c];
    __syncthreads();
#pragma unroll
    for (int ks = 0; ks < 2; ks++) {
      s16x8 af[4], bf[4];
#pragma unroll
      for (int m = 0; m < 4; m++)
        af[m] = *(const s16x8*)&As[wr + m * 16 + lm][ks * 32 + lq * 8];
#pragma unroll
      for (int n = 0; n < 4; n++)
        bf[n] = *(const s16x8*)&Bs[wc + n * 16 + lm][ks * 32 + lq * 8];
#pragma unroll
      for (int m = 0; m < 4; m++)
#pragma unroll
        for (int n = 0; n < 4; n++)
          acc[m][n] = mfma_bf16_16x16x32(af[m], bf[n], acc[m][n]);
    }
    kloc += 64;
    if (kloc == 768) { kloc = 0; h++; }
  }
  asm volatile("s_nop 7\n\ts_nop 7");
#pragma unroll
  for (int m = 0; m < 4; m++)
#pragma unroll
    for (int n = 0; n < 4; n++)
#pragma unroll
      for (int r = 0; r < 4; r++) {
        const int grow = m0 + wr + m * 16 + lq * 4 + r;   // b*1024 + q
        const int gcol = n0 + wc + n * 16 + lm;
        out0[(size_t)grow * 768 + gcol] = acc[m][n][r] + v[(size_t)grow * 768 + gcol];
      }
}

__global__ void zero_kernel(f32x4* __restrict__ p, int n4) {
  int i = blockIdx.x * blockDim.x + threadIdx.x;
  const int stride = gridDim.x * blockDim.x;
  f32x4 z;
  z[0] = z[1] = z[2] = z[3] = 0.f;
  for (; i < n4; i += stride) p[i] = z;
}

__global__ __launch_bounds__(256)
void scatter_kernel(const int* __restrict__ kmaxp, float* __restrict__ attn) {
  const int t = blockIdx.x * 256 + threadIdx.x;
  if (t >= NB * NH * SEQ) return;
  attn[((size_t)t << 10) + kmaxp[t]] = 1.0f;
}

// ---------------------------------------------------------------------------
extern "C" void kernel_launch(void* const* d_in, const int* in_sizes, int n_in,
                              void* d_out, int out_size, void* d_ws, size_t ws_size,
                              hipStream_t stream) {
  (void)in_sizes; (void)n_in; (void)out_size; (void)ws_size;
  const float* q       = (const float*)d_in[0];
  const float* k       = (const float*)d_in[1];
  const float* v       = (const float*)d_in[2];
  const float* qk_mask = (const float*)d_in[5];
  const float* k_mask  = (const float*)d_in[6];
  const float* pmask   = (const float*)d_in[7];
  const float* w_qs    = (const float*)d_in[8];
  const float* w_ks    = (const float*)d_in[9];
  const float* w_vs    = (const float*)d_in[10];
  const float* fc      = (const float*)d_in[11];

  float* out0 = (float*)d_out;
  float* attn = out0 + (size_t)NB * SEQ * DVd;          // 3,145,728 floats in

  float* qh = (float*)d_ws;                             // 4096x768 f32
  float* kh = qh + (size_t)NB * SEQ * Ed;               // 4096x768 f32
  unsigned short* Mstb = (unsigned short*)(kh + (size_t)NB * SEQ * Ed);  // 9216x768 bf16
  float2* partials = (float2*)((char*)Mstb + (size_t)HVd * 768 * sizeof(unsigned short));
  int* kmaxp = (int*)(partials + (size_t)NB * NH * SEQ * 8);

  // 1) Q/K head projections (fp32 — argmax precision path)
  gemm_f32_kernel<<<dim3(32, 6), 256, 0, stream>>>(q, w_qs, qh, NB * SEQ, Ed, Ed);
  gemm_f32_kernel<<<dim3(32, 6), 256, 0, stream>>>(k, w_ks, kh, NB * SEQ, Ed, Ed);

  // 2) masked score argmax (topk+softmax+renorm collapse to this)
  score_argmax_kernel<<<dim3(8, 8, NB * NH), 256, 0, stream>>>(
      qh, kh, qk_mask, k_mask, pmask, partials);
  argmax_reduce_kernel<<<dim3((NB * NH * SEQ + 255) / 256), 256, 0, stream>>>(partials, kmaxp);

  // 3) fused per-head matrix M_h = w_vs_h @ fc_h  (bf16 MFMA)
  wvfc_gemm_kernel<<<dim3(6, 6, NH), 256, 0, stream>>>(w_vs, fc, Mstb);

  // 4) out0 = gather(v, kmax) @ Mstack + v
  gather_gemm_kernel<<<dim3(32, 6), 256, 0, stream>>>(v, Mstb, kmaxp, out0);

  // 5) attn output = one-hot(kmax)
  zero_kernel<<<dim3(2048), 256, 0, stream>>>((f32x4*)attn,
                                              (int)((size_t)NB * NH * SEQ * SEQ / 4));
  scatter_kernel<<<dim3((NB * NH * SEQ + 255) / 256), 256, 0, stream>>>(kmaxp, attn);
}

// Round 2
// 471.175 us; speedup vs baseline: 1.7662x; 1.7662x over previous
//
#include <hip/hip_runtime.h>

// Problem constants
constexpr int NB  = 4;
constexpr int NH  = 12;
constexpr int SEQ = 1024;   // LQ == LK
constexpr int DKd = 64;
constexpr int DVd = 768;
constexpr int Ed  = 768;    // E == H*DK
constexpr int HVd = 9216;   // H*DV

typedef float f32x4 __attribute__((ext_vector_type(4)));
typedef short s16x8 __attribute__((ext_vector_type(8)));

__device__ __forceinline__ unsigned short f2bf(float f) {
  unsigned int u = __builtin_bit_cast(unsigned int, f);
  u += 0x7fffu + ((u >> 16) & 1u);          // RNE
  return (unsigned short)(u >> 16);
}

__device__ __forceinline__ float bf2f_lo(unsigned int u) {
  return __builtin_bit_cast(float, u << 16);
}
__device__ __forceinline__ float bf2f_hi(unsigned int u) {
  return __builtin_bit_cast(float, u & 0xffff0000u);
}

__device__ __forceinline__ f32x4 mfma_bf16_16x16x32(s16x8 a, s16x8 b, f32x4 c) {
  asm("v_mfma_f32_16x16x32_bf16 %0, %1, %2, %0" : "+v"(c) : "v"(a), "v"(b));
  return c;
}

#define GLOAD16(g, l)                                                          \
  __builtin_amdgcn_global_load_lds(                                            \
      (const __attribute__((address_space(1))) unsigned int*)(g),              \
      (__attribute__((address_space(3))) unsigned int*)(l), 16, 0, 0)

// ---------------------------------------------------------------------------
// v (f32) -> Vbf (bf16), elementwise
// ---------------------------------------------------------------------------
__global__ __launch_bounds__(256)
void cvt_bf16_kernel(const float* __restrict__ v, unsigned short* __restrict__ Vbf, int n4) {
  int i = blockIdx.x * 256 + threadIdx.x;
  const int stride = gridDim.x * 256;
  for (; i < n4; i += stride) {
    const f32x4 x = *(const f32x4*)&v[(size_t)i * 4];
    uint2 u;
    u.x = (unsigned)f2bf(x[0]) | ((unsigned)f2bf(x[1]) << 16);
    u.y = (unsigned)f2bf(x[2]) | ((unsigned)f2bf(x[3]) << 16);
    *(uint2*)&Vbf[(size_t)i * 4] = u;
  }
}

// ---------------------------------------------------------------------------
// Fused q/k head projections (fp32 — argmax precision path).
// C[M,768] = A[M,768] @ B[768,768]; 64x64 tile, BK=16, grid (64,12,2).
// ---------------------------------------------------------------------------
__global__ __launch_bounds__(256)
void qkproj_kernel(const float* __restrict__ q, const float* __restrict__ k,
                   const float* __restrict__ w_qs, const float* __restrict__ w_ks,
                   float* __restrict__ qh, float* __restrict__ kh) {
  const float* A  = blockIdx.z ? k : q;
  const float* Bw = blockIdx.z ? w_ks : w_qs;
  float* C        = blockIdx.z ? kh : qh;
  __shared__ float As[16][68];   // [k][m] (+4 pad)
  __shared__ float Bs[16][68];   // [k][n]
  const int tid = threadIdx.x;
  const int m0 = blockIdx.x * 64, n0 = blockIdx.y * 64;
  const int ty = tid >> 4, tx = tid & 15;
  const int arow = tid >> 2, akc = (tid & 3) * 4;
  const int bkr = tid >> 4, bnc = (tid & 15) * 4;

  float acc[4][4];
#pragma unroll
  for (int i = 0; i < 4; i++)
#pragma unroll
    for (int j = 0; j < 4; j++) acc[i][j] = 0.f;

  for (int k0 = 0; k0 < 768; k0 += 16) {
    const f32x4 av = *(const f32x4*)&A[(size_t)(m0 + arow) * 768 + k0 + akc];
    const f32x4 bv = *(const f32x4*)&Bw[(size_t)(k0 + bkr) * 768 + n0 + bnc];
    __syncthreads();
#pragma unroll
    for (int c = 0; c < 4; c++) As[akc + c][arow] = av[c];
    *(f32x4*)&Bs[bkr][bnc] = bv;
    __syncthreads();
#pragma unroll
    for (int kk = 0; kk < 16; kk++) {
      const f32x4 a = *(const f32x4*)&As[kk][ty * 4];
      const f32x4 b = *(const f32x4*)&Bs[kk][tx * 4];
#pragma unroll
      for (int i = 0; i < 4; i++)
#pragma unroll
        for (int j = 0; j < 4; j++) acc[i][j] += a[i] * b[j];
    }
  }
#pragma unroll
  for (int i = 0; i < 4; i++) {
    f32x4 o;
#pragma unroll
    for (int j = 0; j < 4; j++) o[j] = acc[i][j];
    *(f32x4*)&C[(size_t)(m0 + ty * 4 + i) * 768 + n0 + tx * 4] = o;
  }
}

// ---------------------------------------------------------------------------
// Scores + per-128-k-block argmax (masked). Unchanged from round 1.
// ---------------------------------------------------------------------------
__global__ __launch_bounds__(256)
void score_argmax_kernel(const float* __restrict__ qh, const float* __restrict__ kh,
                         const float* __restrict__ qk_mask, const float* __restrict__ k_mask,
                         const float* __restrict__ pmask, float2* __restrict__ partials) {
  __shared__ float QsT[64][128];   // [d][q]
  __shared__ float KsT[64][128];   // [d][k]
  const int bh = blockIdx.z;
  const int b = bh / NH, h = bh % NH;
  const int q0 = blockIdx.y * 128;
  const int k0 = blockIdx.x * 128;
  const int tid = threadIdx.x;
  const int ty = tid >> 4, tx = tid & 15;

  const int row = tid >> 1;
  const int cb = (tid & 1) * 32;
  const float* qsrc = qh + (size_t)(b * SEQ + q0 + row) * Ed + h * DKd + cb;
  const float* ksrc = kh + (size_t)(b * SEQ + k0 + row) * Ed + h * DKd + cb;
#pragma unroll
  for (int i = 0; i < 8; i++) {
    const f32x4 qv = *(const f32x4*)&qsrc[4 * i];
    const f32x4 kv = *(const f32x4*)&ksrc[4 * i];
#pragma unroll
    for (int c = 0; c < 4; c++) {
      QsT[cb + 4 * i + c][row] = qv[c];
      KsT[cb + 4 * i + c][row] = kv[c];
    }
  }
  __syncthreads();

  float acc[8][8];
#pragma unroll
  for (int i = 0; i < 8; i++)
#pragma unroll
    for (int j = 0; j < 8; j++) acc[i][j] = 0.f;

#pragma unroll 8
  for (int kk = 0; kk < 64; kk++) {
    const f32x4 a0 = *(const f32x4*)&QsT[kk][ty * 8];
    const f32x4 a1 = *(const f32x4*)&QsT[kk][ty * 8 + 4];
    const f32x4 b0 = *(const f32x4*)&KsT[kk][tx * 8];
    const f32x4 b1 = *(const f32x4*)&KsT[kk][tx * 8 + 4];
#pragma unroll
    for (int i = 0; i < 4; i++)
#pragma unroll
      for (int j = 0; j < 4; j++) {
        acc[i][j]         += a0[i] * b0[j];
        acc[i][j + 4]     += a0[i] * b1[j];
        acc[i + 4][j]     += a1[i] * b0[j];
        acc[i + 4][j + 4] += a1[i] * b1[j];
      }
  }

  const int kg0 = k0 + tx * 8;
  const f32x4 km0 = *(const f32x4*)&k_mask[b * SEQ + kg0];
  const f32x4 km1 = *(const f32x4*)&k_mask[b * SEQ + kg0 + 4];
#pragma unroll
  for (int i = 0; i < 8; i++) {
    const int qg = q0 + ty * 8 + i;
    const size_t base = (size_t)(b * SEQ + qg) * SEQ + kg0;
    const f32x4 qm0 = *(const f32x4*)&qk_mask[base];
    const f32x4 qm1 = *(const f32x4*)&qk_mask[base + 4];
    const f32x4 pm0 = *(const f32x4*)&pmask[base];
    const f32x4 pm1 = *(const f32x4*)&pmask[base + 4];
    float bv = -3.0e38f;
    int bi = 0;
#pragma unroll
    for (int j = 0; j < 4; j++) {
      const float s = acc[i][j] * 0.125f + qm0[j] + km0[j];
      if (pm0[j] > 0.f && s > bv) { bv = s; bi = kg0 + j; }
    }
#pragma unroll
    for (int j = 0; j < 4; j++) {
      const float s = acc[i][4 + j] * 0.125f + qm1[j] + km1[j];
      if (pm1[j] > 0.f && s > bv) { bv = s; bi = kg0 + 4 + j; }
    }
#pragma unroll
    for (int off = 1; off < 16; off <<= 1) {
      const float ov = __shfl_xor(bv, off);
      const int   oi = __shfl_xor(bi, off);
      if (ov > bv || (ov == bv && oi < bi)) { bv = ov; bi = oi; }
    }
    if (tx == 0)
      partials[(size_t)(bh * SEQ + qg) * 8 + blockIdx.x] =
          make_float2(bv, __int_as_float(bi));
  }
}

__global__ __launch_bounds__(256)
void argmax_reduce_kernel(const float2* __restrict__ partials, int* __restrict__ kmaxp) {
  const int t = blockIdx.x * 256 + threadIdx.x;
  if (t >= NB * NH * SEQ) return;
  const float2* p = partials + (size_t)t * 8;
  float bv = -3.0e38f;
  int bi = 0;
#pragma unroll
  for (int i = 0; i < 8; i++) {
    const float vv = p[i].x;
    const int ii = __float_as_int(p[i].y);
    if (vv > bv) { bv = vv; bi = ii; }
  }
  kmaxp[t] = bi;
}

// ---------------------------------------------------------------------------
// MstbT[h][n][k] = (w_vs[:,h*768:+768] @ fc[h*768:+768,:])^T  (bf16)
// ---------------------------------------------------------------------------
__global__ __launch_bounds__(256)
void wvfc_gemm_kernel(const float* __restrict__ wvs, const float* __restrict__ fcw,
                      unsigned short* __restrict__ MstbT) {
  __shared__ unsigned short As[128][72];   // [m(d)][k]  (+8 pad)
  __shared__ unsigned short Bs[128][72];   // [n][k]  (transposed B)
  const int tid = threadIdx.x;
  const int h = blockIdx.z;
  const int m0 = blockIdx.x * 128, n0 = blockIdx.y * 128;
  const int wid = tid >> 6, lane = tid & 63;
  const int wr = (wid >> 1) * 64, wc = (wid & 1) * 64;
  const int lm = lane & 15, lq = lane >> 4;
  const int ar = tid >> 1, acb = (tid & 1) * 32;
  const int br = tid >> 2, bnb = (tid & 3) * 32;

  f32x4 acc[4][4];
#pragma unroll
  for (int m = 0; m < 4; m++)
#pragma unroll
    for (int n = 0; n < 4; n++)
#pragma unroll
      for (int r = 0; r < 4; r++) acc[m][n][r] = 0.f;

  for (int k0 = 0; k0 < 768; k0 += 64) {
    const float* asrc = wvs + (size_t)(m0 + ar) * HVd + h * 768 + k0 + acb;
    const float* bsrc = fcw + (size_t)(h * 768 + k0 + br) * 768 + n0 + bnb;
    f32x4 a4[8], b4[8];
#pragma unroll
    for (int i = 0; i < 8; i++) a4[i] = *(const f32x4*)&asrc[4 * i];
#pragma unroll
    for (int i = 0; i < 8; i++) b4[i] = *(const f32x4*)&bsrc[4 * i];
    __syncthreads();
#pragma unroll
    for (int i = 0; i < 4; i++) {
      s16x8 pk;
#pragma unroll
      for (int j = 0; j < 8; j++) pk[j] = (short)f2bf(a4[2 * i + (j >> 2)][j & 3]);
      *(s16x8*)&As[ar][acb + 8 * i] = pk;
    }
#pragma unroll
    for (int i = 0; i < 8; i++)
#pragma unroll
      for (int c = 0; c < 4; c++) Bs[bnb + 4 * i + c][br] = f2bf(b4[i][c]);
    __syncthreads();
#pragma unroll
    for (int ks = 0; ks < 2; ks++) {
      s16x8 af[4], bfr[4];
#pragma unroll
      for (int m = 0; m < 4; m++)
        af[m] = *(const s16x8*)&As[wr + m * 16 + lm][ks * 32 + lq * 8];
#pragma unroll
      for (int n = 0; n < 4; n++)
        bfr[n] = *(const s16x8*)&Bs[wc + n * 16 + lm][ks * 32 + lq * 8];
#pragma unroll
      for (int m = 0; m < 4; m++)
#pragma unroll
        for (int n = 0; n < 4; n++)
          acc[m][n] = mfma_bf16_16x16x32(af[m], bfr[n], acc[m][n]);
    }
  }
  asm volatile("s_nop 7\n\ts_nop 7");
  // transposed write: MstbT[(h*768 + out_col)*768 + d], 4 consecutive d per lane (8B)
#pragma unroll
  for (int m = 0; m < 4; m++)
#pragma unroll
    for (int n = 0; n < 4; n++) {
      const int grow0 = m0 + wr + m * 16 + lq * 4;      // d (k of ugemm)
      const int gcol  = n0 + wc + n * 16 + lm;          // output col (n of ugemm)
      uint2 u;
      u.x = (unsigned)f2bf(acc[m][n][0]) | ((unsigned)f2bf(acc[m][n][1]) << 16);
      u.y = (unsigned)f2bf(acc[m][n][2]) | ((unsigned)f2bf(acc[m][n][3]) << 16);
      *(uint2*)&MstbT[(size_t)(h * 768 + gcol) * 768 + grow0] = u;
    }
}

// ---------------------------------------------------------------------------
// U[hg][4096][768p] = Vbf[4096][768] @ M_{h0+hg}  (bf16, m97-style gload_lds)
// Columns stored packed-permuted: within each 64-col chunk, short position
// p = lm*4 + n  holds actual col c = n*16 + lm  (lm=0..15, n=0..3).
// ---------------------------------------------------------------------------
__global__ __launch_bounds__(256)
void ugemm_kernel(const unsigned short* __restrict__ Vbf,
                  const unsigned short* __restrict__ MstbT,
                  unsigned short* __restrict__ U, int h0) {
  __shared__ unsigned short As[128 * 64];  // [m 128][k 64] linear
  __shared__ unsigned short Bs[128 * 64];  // [n 128][k 64] linear
  const int tid = threadIdx.x;
  const int h = h0 + blockIdx.z;
  const int m0 = blockIdx.x * 128, n0 = blockIdx.y * 128;
  const int wid = tid >> 6, lane = tid & 63;
  const int wr = (wid >> 1) * 64, wc = (wid & 1) * 64;
  const int lm = lane & 15, lq = lane >> 4;
  const int srow = tid >> 3, scol = (tid & 7) * 8;     // stage: row-in-32, col
  const int ldst = (tid >> 6) * 512;                    // wave-uniform LDS base (shorts)

  const unsigned short* asrc = Vbf + (size_t)(m0 + srow) * 768 + scol;
  const unsigned short* bsrc = MstbT + (size_t)(h * 768 + n0 + srow) * 768 + scol;

  f32x4 acc[4][4];
#pragma unroll
  for (int m = 0; m < 4; m++)
#pragma unroll
    for (int n = 0; n < 4; n++)
#pragma unroll
      for (int r = 0; r < 4; r++) acc[m][n][r] = 0.f;

  for (int k0 = 0; k0 < 768; k0 += 64) {
#pragma unroll
    for (int j = 0; j < 4; j++)
      GLOAD16(asrc + (size_t)j * 32 * 768 + k0, &As[j * 2048 + ldst]);
#pragma unroll
    for (int j = 0; j < 4; j++)
      GLOAD16(bsrc + (size_t)j * 32 * 768 + k0, &Bs[j * 2048 + ldst]);
    __syncthreads();
#pragma unroll
    for (int ks = 0; ks < 2; ks++) {
      s16x8 af[4], bfr[4];
#pragma unroll
      for (int m = 0; m < 4; m++)
        af[m] = *(const s16x8*)&As[(wr + m * 16 + lm) * 64 + ks * 32 + lq * 8];
#pragma unroll
      for (int n = 0; n < 4; n++)
        bfr[n] = *(const s16x8*)&Bs[(wc + n * 16 + lm) * 64 + ks * 32 + lq * 8];
#pragma unroll
      for (int m = 0; m < 4; m++)
#pragma unroll
        for (int n = 0; n < 4; n++)
          acc[m][n] = mfma_bf16_16x16x32(af[m], bfr[n], acc[m][n]);
    }
    __syncthreads();
  }
  asm volatile("s_nop 7\n\ts_nop 7");
  const size_t urow0 = (size_t)blockIdx.z * 4096;
#pragma unroll
  for (int m = 0; m < 4; m++)
#pragma unroll
    for (int r = 0; r < 4; r++) {
      const int row = m0 + wr + m * 16 + lq * 4 + r;
      uint2 u;
      u.x = (unsigned)f2bf(acc[m][0][r]) | ((unsigned)f2bf(acc[m][1][r]) << 16);
      u.y = (unsigned)f2bf(acc[m][2][r]) | ((unsigned)f2bf(acc[m][3][r]) << 16);
      *(uint2*)&U[(urow0 + row) * 768 + n0 + wc + lm * 4] = u;
    }
}

// ---------------------------------------------------------------------------
// out0[row,:] (+)= sum_hg U[hg][kmax][:]  (+ v residual on first pass)
// One block (192 thr) per output row; inverse col-perm applied on read.
// ---------------------------------------------------------------------------
__global__ __launch_bounds__(192)
void gathersum_kernel(const unsigned short* __restrict__ U, const int* __restrict__ kmaxp,
                      const float* __restrict__ v, float* __restrict__ out0, int h0) {
  const int row = blockIdx.x;           // b*1024 + q
  const int b = row >> 10, q = row & 1023;
  const int t = threadIdx.x;            // 0..191
  float a0 = 0.f, a1 = 0.f, a2 = 0.f, a3 = 0.f;
#pragma unroll
  for (int hg = 0; hg < 6; hg++) {
    const int g = kmaxp[((b * NH + h0 + hg) << 10) + q];
    const uint2 u = *(const uint2*)&U[((size_t)hg * 4096 + (b << 10) + g) * 768 + t * 4];
    a0 += bf2f_lo(u.x);
    a1 += bf2f_hi(u.x);
    a2 += bf2f_lo(u.y);
    a3 += bf2f_hi(u.y);
  }
  const int chunk = t >> 4, lmm = t & 15;
  const size_t ob = (size_t)row * 768 + chunk * 64 + lmm;
  if (h0 == 0) {
    out0[ob +  0] = a0 + v[ob +  0];
    out0[ob + 16] = a1 + v[ob + 16];
    out0[ob + 32] = a2 + v[ob + 32];
    out0[ob + 48] = a3 + v[ob + 48];
  } else {
    out0[ob +  0] += a0;
    out0[ob + 16] += a1;
    out0[ob + 32] += a2;
    out0[ob + 48] += a3;
  }
}

__global__ void zero_kernel(f32x4* __restrict__ p, int n4) {
  int i = blockIdx.x * blockDim.x + threadIdx.x;
  const int stride = gridDim.x * blockDim.x;
  f32x4 z;
  z[0] = z[1] = z[2] = z[3] = 0.f;
  for (; i < n4; i += stride) p[i] = z;
}

__global__ __launch_bounds__(256)
void scatter_kernel(const int* __restrict__ kmaxp, float* __restrict__ attn) {
  const int t = blockIdx.x * 256 + threadIdx.x;
  if (t >= NB * NH * SEQ) return;
  attn[((size_t)t << 10) + kmaxp[t]] = 1.0f;
}

// ---------------------------------------------------------------------------
extern "C" void kernel_launch(void* const* d_in, const int* in_sizes, int n_in,
                              void* d_out, int out_size, void* d_ws, size_t ws_size,
                              hipStream_t stream) {
  (void)in_sizes; (void)n_in; (void)out_size; (void)ws_size;
  const float* q       = (const float*)d_in[0];
  const float* k       = (const float*)d_in[1];
  const float* v       = (const float*)d_in[2];
  const float* qk_mask = (const float*)d_in[5];
  const float* k_mask  = (const float*)d_in[6];
  const float* pmask   = (const float*)d_in[7];
  const float* w_qs    = (const float*)d_in[8];
  const float* w_ks    = (const float*)d_in[9];
  const float* w_vs    = (const float*)d_in[10];
  const float* fc      = (const float*)d_in[11];

  float* out0 = (float*)d_out;
  float* attn = out0 + (size_t)NB * SEQ * DVd;

  // workspace layout (58.4 MB total):
  char* ws = (char*)d_ws;
  unsigned short* MstbT = (unsigned short*)ws;                 // 14,155,776 B
  unsigned short* Vbf   = (unsigned short*)(ws + 14155776);    //  6,291,456 B
  int* kmaxp            = (int*)(ws + 20447232);               //    196,608 B
  char* ureg            = ws + 20643840;
  unsigned short* U     = (unsigned short*)ureg;               // 37,748,736 B
  // qh/kh/partials overlap U (dead before ugemm runs):
  float* qh             = (float*)ureg;                        // 12,582,912 B
  float* kh             = (float*)(ureg + 12582912);           // 12,582,912 B
  float2* partials      = (float2*)(ureg + 25165824);          //  3,145,728 B

  // 1) v -> bf16
  cvt_bf16_kernel<<<dim3(3072), 256, 0, stream>>>(v, Vbf, NB * SEQ * DVd / 4);

  // 2) fused q/k projections (fp32)
  qkproj_kernel<<<dim3(64, 12, 2), 256, 0, stream>>>(q, k, w_qs, w_ks, qh, kh);

  // 3) masked score argmax
  score_argmax_kernel<<<dim3(8, 8, NB * NH), 256, 0, stream>>>(
      qh, kh, qk_mask, k_mask, pmask, partials);
  argmax_reduce_kernel<<<dim3((NB * NH * SEQ + 255) / 256), 256, 0, stream>>>(partials, kmaxp);

  // 4) per-head M^T = (w_vs_h @ fc_h)^T  (bf16)
  wvfc_gemm_kernel<<<dim3(6, 6, NH), 256, 0, stream>>>(w_vs, fc, MstbT);

  // 5) two head-groups: dense U_h = Vbf @ M_h, then gather+sum into out0
  ugemm_kernel<<<dim3(32, 6, 6), 256, 0, stream>>>(Vbf, MstbT, U, 0);
  gathersum_kernel<<<dim3(NB * SEQ), 192, 0, stream>>>(U, kmaxp, v, out0, 0);
  ugemm_kernel<<<dim3(32, 6, 6), 256, 0, stream>>>(Vbf, MstbT, U, 6);
  gathersum_kernel<<<dim3(NB * SEQ), 192, 0, stream>>>(U, kmaxp, v, out0, 6);

  // 6) attn output = one-hot(kmax)
  zero_kernel<<<dim3(2048), 256, 0, stream>>>((f32x4*)attn,
                                              (int)((size_t)NB * NH * SEQ * SEQ / 4));
  scatter_kernel<<<dim3((NB * NH * SEQ + 255) / 256), 256, 0, stream>>>(kmaxp, attn);
}